// Round 1
// baseline (22534.425 us; speedup 1.0000x reference)
//
#include <hip/hip_runtime.h>

// GRU: T=512 steps, B=64, I=H=1024, fp32 in/out.
// R3: single persistent kernel for the whole recurrence.
//  - 64 WGs x 512 threads (co-resident on 256 CUs), each WG owns 16 output
//    columns for all three gates. wave w: gate parity w&1, M-tile w>>1.
//  - 2 custom device-scope grid barriers per step (h -> {z,r}, r*h -> c).
//  - x-projections (h-independent) computed in the barrier shadow from an
//    LDS-staged bf16 copy of x_t (XOR-swizzled vs 16-way bank conflict).
//  - z kept in registers of the wave that finishes c (no zbuf round-trip).
// Numerics identical to R2: bf16 MFMA, fp32 accum, fp32 h path.

typedef __bf16 bf16x8 __attribute__((ext_vector_type(8)));
typedef float  f32x4  __attribute__((ext_vector_type(4)));

#define TT  512
#define BB  64
#define HH  1024
#define BHH (BB * HH)
#define NWG 64
#define NT  512

// ---------------------------------------------------------------------------
// one-time weight fp32 -> bf16
// ---------------------------------------------------------------------------
__global__ __launch_bounds__(256) void cvt_w(const float* __restrict__ src,
                                             __bf16* __restrict__ dst) {
    int i = (blockIdx.x * 256 + threadIdx.x) * 4;
    f32x4 v = *(const f32x4*)(src + i);
    __bf16 o[4] = {(__bf16)v.x, (__bf16)v.y, (__bf16)v.z, (__bf16)v.w};
    *(ulong1*)(dst + i) = *(ulong1*)o;
}

// ---------------------------------------------------------------------------
// init h (fp32 + bf16 copies) and zero the grid barrier
// ---------------------------------------------------------------------------
__global__ __launch_bounds__(256) void gru_init(const float* __restrict__ hid,
                                                float* __restrict__ h_f,
                                                __bf16* __restrict__ h_b,
                                                unsigned* __restrict__ bar) {
    int i = blockIdx.x * 256 + threadIdx.x;
    if (i < BHH) {
        float v = hid[i];
        h_f[i] = v;
        h_b[i] = (__bf16)v;
    }
    if (i == 0) { bar[0] = 0u; bar[1] = 0u; }
}

// ---------------------------------------------------------------------------
// GEMM helpers. MFMA maps (m89-verified): A[m=lane&15][k=(lane>>4)*8+j],
// B[col=lane&15][k same]; C/D col=lane&15, row=(lane>>4)*4+reg.
// ---------------------------------------------------------------------------
template<int NK>
__device__ __forceinline__ f32x4 mm_g(const __bf16* __restrict__ A,
                                      const __bf16* __restrict__ B, f32x4 acc) {
    #pragma unroll 8
    for (int k = 0; k < NK; k += 32) {
        bf16x8 a = *(const bf16x8*)(A + k);
        bf16x8 b = *(const bf16x8*)(B + k);
        acc = __builtin_amdgcn_mfma_f32_16x16x32_bf16(a, b, acc, 0, 0, 0);
    }
    return acc;
}

// A from LDS-staged x (bf16, XOR-swizzled rows of 2048 B)
template<int NK>
__device__ __forceinline__ f32x4 mm_x(const char* xl, unsigned rowb,
                                      unsigned coff, unsigned rmask,
                                      const __bf16* __restrict__ B, f32x4 acc) {
    #pragma unroll 8
    for (int k = 0; k < NK; k += 32) {
        bf16x8 a = *(const bf16x8*)(xl + rowb + ((coff + (unsigned)(k * 2)) ^ rmask));
        bf16x8 b = *(const bf16x8*)(B + k);
        acc = __builtin_amdgcn_mfma_f32_16x16x32_bf16(a, b, acc, 0, 0, 0);
    }
    return acc;
}

// stage x_t [64][1024] fp32 -> LDS bf16, swizzled: byte ^= (row&7)<<4
__device__ __forceinline__ void stage_x(char* xl, const float* __restrict__ xt) {
    const int tid = threadIdx.x;
    #pragma unroll
    for (int p = 0; p < 16; ++p) {
        int c = p * NT + tid;                 // 16B-chunk id, 8192 total
        unsigned row = (unsigned)(c >> 7);    // 128 chunks per row
        unsigned off = (unsigned)(c & 127) << 4;
        const float* s = xt + ((size_t)c << 3);
        f32x4 v0 = *(const f32x4*)s;
        f32x4 v1 = *(const f32x4*)(s + 4);
        bf16x8 ov;
        ov[0] = (__bf16)v0.x; ov[1] = (__bf16)v0.y; ov[2] = (__bf16)v0.z; ov[3] = (__bf16)v0.w;
        ov[4] = (__bf16)v1.x; ov[5] = (__bf16)v1.y; ov[6] = (__bf16)v1.z; ov[7] = (__bf16)v1.w;
        *(bf16x8*)(xl + row * 2048u + (off ^ ((row & 7u) << 4))) = ov;
    }
}

// ---------------------------------------------------------------------------
// grid barrier: sense via monotonically increasing generation counter.
// bar[0]=arrive count, bar[1]=generation. Agent-scope atomics + threadfence
// (per-XCD L2s are not coherent; plain loads could spin on stale data).
// ---------------------------------------------------------------------------
__device__ __forceinline__ void gbar_arrive(unsigned* bar, unsigned target) {
    __syncthreads();                       // all WG lanes done + stores drained
    if (threadIdx.x == 0) {
        __threadfence();                   // release WG's global writes
        unsigned old = __hip_atomic_fetch_add(&bar[0], 1u, __ATOMIC_ACQ_REL,
                                              __HIP_MEMORY_SCOPE_AGENT);
        if (old == (unsigned)(NWG - 1)) {
            __hip_atomic_store(&bar[0], 0u, __ATOMIC_RELAXED, __HIP_MEMORY_SCOPE_AGENT);
            __hip_atomic_store(&bar[1], target, __ATOMIC_RELEASE, __HIP_MEMORY_SCOPE_AGENT);
        }
    }
}

__device__ __forceinline__ void gbar_wait(unsigned* bar, unsigned target) {
    if (threadIdx.x == 0) {
        while (__hip_atomic_load(&bar[1], __ATOMIC_ACQUIRE, __HIP_MEMORY_SCOPE_AGENT) < target)
            __builtin_amdgcn_s_sleep(2);
        __threadfence();                   // acquire side for subsequent plain loads
    }
    __syncthreads();
}

// ---------------------------------------------------------------------------
// the persistent GRU kernel
// ---------------------------------------------------------------------------
__global__ __launch_bounds__(NT) void gru_fused(
    const float* __restrict__ x,
    const __bf16* __restrict__ Wzh, const __bf16* __restrict__ Wzi,
    const __bf16* __restrict__ Wrh, const __bf16* __restrict__ Wri,
    const __bf16* __restrict__ Wch, const __bf16* __restrict__ Wci,
    const float* __restrict__ bzh, const float* __restrict__ bzi,
    const float* __restrict__ brh, const float* __restrict__ bri,
    const float* __restrict__ bch, const float* __restrict__ bci,
    float* __restrict__ h_f, __bf16* __restrict__ h_b,
    __bf16* __restrict__ rh, unsigned* __restrict__ bar,
    float* __restrict__ out)
{
    __shared__ __align__(16) char smem[132 * 1024];   // 128K x_t + 4K reduce
    char* xl = smem;
    f32x4* red = (f32x4*)(smem + 131072);

    const int wg   = blockIdx.x;
    const int n0   = wg << 4;               // 16 owned output columns
    const int tid  = threadIdx.x;
    const int wv   = tid >> 6;
    const int lane = tid & 63;
    const int rc   = lane & 15;
    const int kg   = lane >> 4;
    const int mt   = wv >> 1;               // M-tile 0..3
    const int odd  = wv & 1;                // 0: z + c-finish, 1: r + c-partial
    const int m0   = mt << 4;

    const int n  = n0 + rc;
    const float bz = bzh[n] + bzi[n];
    const float br = brh[n] + bri[n];
    const float bc = bch[n] + bci[n];

    const int arow = (m0 + rc) * HH + kg * 8;   // A-frag base (h_b / rh)
    const int brow = n * HH + kg * 8;           // B-frag base (weights)
    const unsigned xrowb = (unsigned)(m0 + rc) * 2048u;
    const unsigned xmask = ((unsigned)(m0 + rc) & 7u) << 4;
    const unsigned xcoff = (unsigned)kg * 16u;

    const __bf16* Wh  = odd ? Wrh : Wzh;    // P1 recurrent weight
    const __bf16* Wxi = odd ? Wri : Wzi;    // P1 input weight (shadow GEMM)
    const f32x4 zero = {0.f, 0.f, 0.f, 0.f};

    // prologue: stage x_0, compute first-step x-partials for z/r
    stage_x(xl, x);
    __syncthreads();
    f32x4 px = mm_x<1024>(xl, xrowb, xcoff, xmask, Wxi + brow, zero);

    f32x4 zreg = zero;
    unsigned target = 0;

    for (int t = 0; t < TT; ++t) {
        // ---- P1: z (even) / r + rh (odd) over h_{t-1}, K=1024 ----
        f32x4 acc = mm_g<1024>(h_b + arow, Wh + brow, zero);
        if (odd) {
            #pragma unroll
            for (int r2 = 0; r2 < 4; ++r2) {
                int idx = (m0 + kg * 4 + r2) * HH + n;
                float s = 1.f / (1.f + __expf(-(acc[r2] + px[r2] + br)));
                rh[idx] = (__bf16)(s * h_f[idx]);
            }
        } else {
            #pragma unroll
            for (int r2 = 0; r2 < 4; ++r2)
                zreg[r2] = 1.f / (1.f + __expf(-(acc[r2] + px[r2] + bz)));
        }
        target++;
        gbar_arrive(bar, target);
        // B1 shadow: xc partial (K-half by parity) from LDS x_t
        f32x4 pacc = mm_x<512>(xl, xrowb, xcoff + (odd ? 1024u : 0u), xmask,
                               Wci + brow + (odd ? 512 : 0), zero);
        gbar_wait(bar, target);

        // ---- P2: c over r*h, K-half per parity; pair-reduce in LDS ----
        pacc = mm_g<512>(rh + arow + (odd ? 512 : 0),
                         Wch + brow + (odd ? 512 : 0), pacc);
        if (odd) red[mt * 64 + lane] = pacc;
        __syncthreads();
        if (!odd) {
            f32x4 other = red[mt * 64 + lane];
            #pragma unroll
            for (int r2 = 0; r2 < 4; ++r2) {
                int idx = (m0 + kg * 4 + r2) * HH + n;
                float c  = tanhf(pacc[r2] + other[r2] + bc);
                float ho = h_f[idx];
                float hn = (1.f - zreg[r2]) * ho + zreg[r2] * c;
                h_f[idx] = hn;
                h_b[idx] = (__bf16)hn;
                out[(size_t)t * BHH + idx] = hn;
                if (t == TT - 1) out[(size_t)TT * BHH + idx] = hn;
            }
        }
        target++;
        gbar_arrive(bar, target);
        // B2 shadow: stage x_{t+1}, compute next step's z/r x-partials
        if (t + 1 < TT) {
            stage_x(xl, x + (size_t)(t + 1) * BHH);
            __syncthreads();
            px = mm_x<1024>(xl, xrowb, xcoff, xmask, Wxi + brow, zero);
        }
        gbar_wait(bar, target);
    }
}

// ---------------------------------------------------------------------------
extern "C" void kernel_launch(void* const* d_in, const int* in_sizes, int n_in,
                              void* d_out, int out_size, void* d_ws, size_t ws_size,
                              hipStream_t stream) {
    const float* x   = (const float*)d_in[0];
    const float* hid = (const float*)d_in[1];
    const float* Wzi = (const float*)d_in[2];
    const float* bzi = (const float*)d_in[3];
    const float* Wzh = (const float*)d_in[4];
    const float* bzh = (const float*)d_in[5];
    const float* Wri = (const float*)d_in[6];
    const float* bri = (const float*)d_in[7];
    const float* Wrh = (const float*)d_in[8];
    const float* brh = (const float*)d_in[9];
    const float* Wci = (const float*)d_in[10];
    const float* bci = (const float*)d_in[11];
    const float* Wch = (const float*)d_in[12];
    const float* bch = (const float*)d_in[13];
    float* out = (float*)d_out;

    // workspace layout (~12.5 MB)
    char* ws = (char*)d_ws;
    const size_t WSZ = (size_t)HH * HH * sizeof(__bf16);   // 2 MB per matrix
    __bf16* Wzh_b = (__bf16*)(ws + 0 * WSZ);
    __bf16* Wzi_b = (__bf16*)(ws + 1 * WSZ);
    __bf16* Wrh_b = (__bf16*)(ws + 2 * WSZ);
    __bf16* Wri_b = (__bf16*)(ws + 3 * WSZ);
    __bf16* Wch_b = (__bf16*)(ws + 4 * WSZ);
    __bf16* Wci_b = (__bf16*)(ws + 5 * WSZ);
    char* p = ws + 6 * WSZ;
    float*    h_f = (float*)p;    p += (size_t)BHH * 4;    // 256 KB
    __bf16*   h_b = (__bf16*)p;   p += (size_t)BHH * 2;    // 128 KB
    __bf16*   rh  = (__bf16*)p;   p += (size_t)BHH * 2;    // 128 KB
    unsigned* bar = (unsigned*)p;                          // 16 B

    const int cvt_blocks = (HH * HH) / (256 * 4);   // 1024
    cvt_w<<<cvt_blocks, 256, 0, stream>>>(Wzh, Wzh_b);
    cvt_w<<<cvt_blocks, 256, 0, stream>>>(Wzi, Wzi_b);
    cvt_w<<<cvt_blocks, 256, 0, stream>>>(Wrh, Wrh_b);
    cvt_w<<<cvt_blocks, 256, 0, stream>>>(Wri, Wri_b);
    cvt_w<<<cvt_blocks, 256, 0, stream>>>(Wch, Wch_b);
    cvt_w<<<cvt_blocks, 256, 0, stream>>>(Wci, Wci_b);
    gru_init<<<BHH / 256, 256, 0, stream>>>(hid, h_f, h_b, bar);

    gru_fused<<<NWG, NT, 0, stream>>>(x,
                                      Wzh_b, Wzi_b, Wrh_b, Wri_b, Wch_b, Wci_b,
                                      bzh, bzi, brh, bri, bch, bci,
                                      h_f, h_b, rh, bar, out);
}

// Round 2
// 10397.847 us; speedup vs baseline: 2.1672x; 2.1672x over previous
//
#include <hip/hip_runtime.h>

// GRU: T=512, B=64, I=H=1024, fp32 interface.
// R4: persistent kernel with FENCE-FREE grid barrier.
//  - R3 post-mortem: ACQUIRE spin + __threadfence => buffer_inv/wbl2 per
//    iteration, invalidating per-XCD L2 constantly (MfmaUtil 0.7%). Fix:
//    relaxed-only monotonic barrier; cross-WG data (h_b, rh) goes through
//    the coherence point via sc0/sc1 bypass loads/stores, so no cache
//    maintenance is ever needed.
//  - Recurrent weights (Wzh,Wrh,Wch column slices) live in LDS (96 KB,
//    XOR-swizzled): immune to everything.
//  - h_f is WG-local -> LDS (4 KB). z stays in registers.
//  - x-projections precomputed (fp32) by x_pre when ws_size allows
//    (~397 MB); else computed in barrier-shadow from L2-cached x.
//  - A-fragments read directly from global (bypass) with a 2-block-deep
//    counted-vmcnt pipeline (8 loads/block, vmcnt(8), sched_barrier).

typedef __bf16 bf16x8 __attribute__((ext_vector_type(8)));
typedef float  f32x4  __attribute__((ext_vector_type(4)));
typedef unsigned int u32x4 __attribute__((ext_vector_type(4)));

#define TT  512
#define BB  64
#define HH  1024
#define BHH (BB * HH)
#define NWG 64
#define NT  512

// ---------------------------------------------------------------------------
// one-time weight fp32 -> bf16
// ---------------------------------------------------------------------------
__global__ __launch_bounds__(256) void cvt_w(const float* __restrict__ src,
                                             __bf16* __restrict__ dst) {
    int i = (blockIdx.x * 256 + threadIdx.x) * 4;
    f32x4 v = *(const f32x4*)(src + i);
    __bf16 o[4] = {(__bf16)v.x, (__bf16)v.y, (__bf16)v.z, (__bf16)v.w};
    *(ulong1*)(dst + i) = *(ulong1*)o;
}

// init h_b (bf16) from hidden, zero barrier
__global__ __launch_bounds__(256) void gru_init(const float* __restrict__ hid,
                                                __bf16* __restrict__ h_b,
                                                unsigned* __restrict__ bar) {
    int i = blockIdx.x * 256 + threadIdx.x;
    if (i < BHH) h_b[i] = (__bf16)hid[i];
    if (i == 0) { bar[0] = 0u; bar[32] = 0u; }
}

// ---------------------------------------------------------------------------
// helpers
// ---------------------------------------------------------------------------
__device__ __forceinline__ bf16x8 ld_cvt8(const float* p) {
    f32x4 a = *(const f32x4*)p;
    f32x4 b = *(const f32x4*)(p + 4);
    bf16x8 r;
    r[0] = (__bf16)a.x; r[1] = (__bf16)a.y; r[2] = (__bf16)a.z; r[3] = (__bf16)a.w;
    r[4] = (__bf16)b.x; r[5] = (__bf16)b.y; r[6] = (__bf16)b.z; r[7] = (__bf16)b.w;
    return r;
}

// 16B cache-bypass load (skips L1+L2: reads the coherence point)
__device__ __forceinline__ bf16x8 ld16_cc(const __bf16* p) {
    u32x4 r;
    asm volatile("global_load_dwordx4 %0, %1, off sc0 sc1" : "=v"(r) : "v"(p));
    return __builtin_bit_cast(bf16x8, r);
}

// 2B write-through store (lands at coherence point; acked by vmcnt)
__device__ __forceinline__ void st2_cc(__bf16* p, float v) {
    unsigned short b = __builtin_bit_cast(unsigned short, (__bf16)v);
    __hip_atomic_store((unsigned short*)p, b, __ATOMIC_RELAXED,
                       __HIP_MEMORY_SCOPE_AGENT);
}

// plain-global GEMM helper (fp32 A with in-reg cvt, bf16 B) - fallback shadows
template<int NK>
__device__ __forceinline__ f32x4 mm_gx(const float* __restrict__ A,
                                       const __bf16* __restrict__ B, f32x4 acc) {
    #pragma unroll 4
    for (int k = 0; k < NK; k += 32) {
        bf16x8 a = ld_cvt8(A + k);
        bf16x8 b = *(const bf16x8*)(B + k);
        acc = __builtin_amdgcn_mfma_f32_16x16x32_bf16(a, b, acc, 0, 0, 0);
    }
    return acc;
}

// Direct-A GEMM: A via bypass loads (2-block pipeline, counted vmcnt),
// B from swizzled LDS. NBLK blocks of K=256. MFMA maps per m89.
template<int NBLK>
__device__ __forceinline__ f32x4 mm_d(const __bf16* Ag, const char* wl,
                                      unsigned bb, unsigned swz, unsigned k0,
                                      unsigned kg, f32x4 acc)
{
    bf16x8 bA[8], bB[8];
    #pragma unroll
    for (int j = 0; j < 8; ++j) bA[j] = ld16_cc(Ag + k0 + j * 32);
    #pragma unroll
    for (int j = 0; j < 8; ++j) bB[j] = ld16_cc(Ag + k0 + 256 + j * 32);
    #pragma unroll
    for (int i = 0; i < NBLK; ++i) {
        if (i + 1 < NBLK) asm volatile("s_waitcnt vmcnt(8)");
        else              asm volatile("s_waitcnt vmcnt(0)");
        __builtin_amdgcn_sched_barrier(0);   // rule #18: pin MFMA below wait
        #pragma unroll
        for (int j = 0; j < 8; ++j) {
            unsigned k = k0 + (unsigned)i * 256u + (unsigned)j * 32u;
            bf16x8 b = *(const bf16x8*)(wl + bb + ((kg * 16u + k * 2u) ^ swz));
            acc = __builtin_amdgcn_mfma_f32_16x16x32_bf16(
                      (i & 1) ? bB[j] : bA[j], b, acc, 0, 0, 0);
        }
        if (i + 2 < NBLK) {
            #pragma unroll
            for (int j = 0; j < 8; ++j)
                ((i & 1) ? bB : bA)[j] = ld16_cc(Ag + k0 + (i + 2) * 256 + j * 32);
        }
    }
    __builtin_amdgcn_sched_barrier(0);
    return acc;
}

__device__ __forceinline__ f32x4 load_xp4(const float* __restrict__ xp, int t,
                                          int m0, int kg, int n) {
    f32x4 r;
    #pragma unroll
    for (int j = 0; j < 4; ++j)
        r[j] = xp[(size_t)(t * BB + m0 + kg * 4 + j) * HH + n];
    return r;
}

// ---------------------------------------------------------------------------
// fence-free grid barrier: monotonic count bar[0], generation bar[32].
// RELAXED only => no buffer_inv / buffer_wbl2, L2 stays warm. Data
// visibility is provided by the bypass loads/stores themselves; the
// __syncthreads in arrive drains vmcnt (stores acked at coherence point)
// before lane0 bumps the count.
// ---------------------------------------------------------------------------
__device__ __forceinline__ void gbar_arrive(unsigned* bar, unsigned target) {
    __syncthreads();
    if (threadIdx.x == 0) {
        unsigned old = __hip_atomic_fetch_add(&bar[0], 1u, __ATOMIC_RELAXED,
                                              __HIP_MEMORY_SCOPE_AGENT);
        if (old == target * (unsigned)NWG - 1u)
            __hip_atomic_store(&bar[32], target, __ATOMIC_RELAXED,
                               __HIP_MEMORY_SCOPE_AGENT);
    }
}

__device__ __forceinline__ void gbar_wait(unsigned* bar, unsigned target) {
    if (threadIdx.x == 0) {
        while (__hip_atomic_load(&bar[32], __ATOMIC_RELAXED,
                                 __HIP_MEMORY_SCOPE_AGENT) < target)
            __builtin_amdgcn_s_sleep(1);
    }
    __syncthreads();
    __builtin_amdgcn_sched_barrier(0);
    asm volatile("" ::: "memory");
}

// ---------------------------------------------------------------------------
// one-shot x-projection GEMM: xp_g = x @ Wg^T (no bias), fp32 out.
// grid: 512 M-blocks x 16 N-blocks, 4 waves/WG, wave = 16 rows x 64 cols x 3.
// ---------------------------------------------------------------------------
__global__ __launch_bounds__(256) void x_pre(
    const float* __restrict__ x,
    const __bf16* __restrict__ Wzi, const __bf16* __restrict__ Wri,
    const __bf16* __restrict__ Wci,
    float* __restrict__ xpz, float* __restrict__ xpr, float* __restrict__ xpc)
{
    const int mb = blockIdx.x >> 4;
    const int nbase = (blockIdx.x & 15) << 6;
    const int w = threadIdx.x >> 6;
    const int lane = threadIdx.x & 63;
    const int rc = lane & 15, kg = lane >> 4;
    const int m = (mb << 6) + (w << 4) + rc;

    const float* A = x + (size_t)m * HH + kg * 8;
    const __bf16* B0 = Wzi + (size_t)(nbase + rc) * HH + kg * 8;
    const __bf16* B1 = Wri + (size_t)(nbase + rc) * HH + kg * 8;
    const __bf16* B2 = Wci + (size_t)(nbase + rc) * HH + kg * 8;

    f32x4 acc[3][4];
    #pragma unroll
    for (int g = 0; g < 3; ++g)
        #pragma unroll
        for (int s = 0; s < 4; ++s) acc[g][s] = {0.f, 0.f, 0.f, 0.f};

    #pragma unroll 2
    for (int k = 0; k < HH; k += 32) {
        bf16x8 a = ld_cvt8(A + k);
        #pragma unroll
        for (int s = 0; s < 4; ++s) {
            const size_t co = (size_t)s * 16 * HH + k;
            acc[0][s] = __builtin_amdgcn_mfma_f32_16x16x32_bf16(a, *(const bf16x8*)(B0 + co), acc[0][s], 0, 0, 0);
            acc[1][s] = __builtin_amdgcn_mfma_f32_16x16x32_bf16(a, *(const bf16x8*)(B1 + co), acc[1][s], 0, 0, 0);
            acc[2][s] = __builtin_amdgcn_mfma_f32_16x16x32_bf16(a, *(const bf16x8*)(B2 + co), acc[2][s], 0, 0, 0);
        }
    }
    const int mrow = (mb << 6) + (w << 4) + (kg << 2);
    #pragma unroll
    for (int s = 0; s < 4; ++s) {
        const int n = nbase + s * 16 + rc;
        #pragma unroll
        for (int r = 0; r < 4; ++r) {
            const size_t o = (size_t)(mrow + r) * HH + n;
            xpz[o] = acc[0][s][r];
            xpr[o] = acc[1][s][r];
            xpc[o] = acc[2][s][r];
        }
    }
}

// ---------------------------------------------------------------------------
// persistent GRU kernel. 64 WGs x 512 thr; WG owns 16 output cols.
// wave wv: M-tile = wv>>1 (16 rows), parity = wv&1 (0: z + c-finish, 1: r).
// ---------------------------------------------------------------------------
template<bool PRE>
__global__ __launch_bounds__(NT) void gru_fused(
    const float* __restrict__ x, const float* __restrict__ hid,
    const __bf16* __restrict__ Wzh, const __bf16* __restrict__ Wrh,
    const __bf16* __restrict__ Wch,
    const __bf16* __restrict__ Wzi, const __bf16* __restrict__ Wri,
    const __bf16* __restrict__ Wci,
    const float* __restrict__ bzh, const float* __restrict__ bzi,
    const float* __restrict__ brh, const float* __restrict__ bri,
    const float* __restrict__ bch, const float* __restrict__ bci,
    __bf16* __restrict__ h_b, __bf16* __restrict__ rh,
    unsigned* __restrict__ bar, float* __restrict__ out,
    const float* __restrict__ xpz, const float* __restrict__ xpr,
    const float* __restrict__ xpc)
{
    __shared__ __align__(16) char smem[106496];  // 96K weights + 4K h_f + 4K red
    char* wl = smem;
    float* h_fl = (float*)(smem + 98304);
    f32x4* red = (f32x4*)(smem + 98304 + 4096);

    const int tid = threadIdx.x;
    const int n0 = blockIdx.x << 4;

    // stage recurrent-weight column slices into LDS, XOR-swizzled rows.
    // LDS row = mat*16 + col (mat 0:Wzh 1:Wrh 2:Wch), 2048 B each;
    // byte ^= (row&7)<<4 kills the 16-way stride-2048 bank conflict.
    #pragma unroll
    for (int it = 0; it < 12; ++it) {
        int c = it * NT + tid;               // 48 rows x 128 chunks
        int row = c >> 7;
        int k8 = c & 127;
        const __bf16* src = row < 16 ? Wzh : (row < 32 ? Wrh : Wch);
        bf16x8 v = *(const bf16x8*)(src + (size_t)(n0 + (row & 15)) * HH + k8 * 8);
        *(bf16x8*)(wl + row * 2048 +
                   (((unsigned)k8 << 4) ^ (((unsigned)row & 7u) << 4))) = v;
    }
    for (int i = tid; i < BB * 16; i += NT)    // h_f[m][c] (WG-local, fp32)
        h_fl[i] = hid[(size_t)(i >> 4) * HH + n0 + (i & 15)];

    const int wv = tid >> 6, lane = tid & 63;
    const int rc = lane & 15;
    const unsigned kg = (unsigned)(lane >> 4);
    const int mt = wv >> 1, odd = wv & 1;
    const int m0 = mt << 4;
    const int n = n0 + rc;

    const float bz = bzh[n] + bzi[n];
    const float br = brh[n] + bri[n];
    const float bc = bch[n] + bci[n];

    const size_t arow = (size_t)(m0 + rc) * HH + kg * 8;  // A-frag base
    const size_t browg = (size_t)n * HH + kg * 8;         // global W row base
    const unsigned swz = ((unsigned)rc & 7u) << 4;
    const unsigned bb1 = ((odd ? 16u : 0u) + (unsigned)rc) * 2048u;
    const unsigned bb2 = (32u + (unsigned)rc) * 2048u;
    const __bf16* Wxi = odd ? Wri : Wzi;
    const float* xp1 = odd ? xpr : xpz;
    const f32x4 vzero = {0.f, 0.f, 0.f, 0.f};

    __syncthreads();

    f32x4 px;
    if constexpr (PRE) px = load_xp4(xp1, 0, m0, (int)kg, n);
    else px = mm_gx<HH>(x + arow, Wxi + browg, vzero);

    f32x4 zreg = vzero, pxc = vzero;

    for (int t = 0; t < TT; ++t) {
        // ---- P1: z (even) / r -> rh (odd), K=1024 over h_{t-1} ----
        f32x4 acc = mm_d<4>(h_b + arow, wl, bb1, swz, 0u, kg, vzero);
        if (odd) {
            #pragma unroll
            for (int r2 = 0; r2 < 4; ++r2) {
                const int m = m0 + (int)kg * 4 + r2;   // C/D row map
                const float s = 1.f / (1.f + __expf(-(acc[r2] + px[r2] + br)));
                st2_cc(rh + (size_t)m * HH + n, s * h_fl[m * 16 + rc]);
            }
        } else {
            #pragma unroll
            for (int r2 = 0; r2 < 4; ++r2)
                zreg[r2] = 1.f / (1.f + __expf(-(acc[r2] + px[r2] + bz)));
        }
        const unsigned tg1 = 2u * (unsigned)t + 1u;
        gbar_arrive(bar, tg1);
        f32x4 pacc0 = vzero;
        if constexpr (PRE) pxc = load_xp4(xpc, t, m0, (int)kg, n);
        else pacc0 = mm_gx<512>(x + (size_t)t * BHH + arow + (odd ? 512 : 0),
                                Wci + browg + (odd ? 512 : 0), vzero);
        gbar_wait(bar, tg1);

        // ---- P2: c over r*h (K-half per parity), pair-reduce, h update ----
        f32x4 pacc = mm_d<2>(rh + arow, wl, bb2, swz, odd ? 512u : 0u, kg, pacc0);
        if (odd) red[mt * 64 + lane] = pacc;
        __syncthreads();
        if (!odd) {
            const f32x4 other = red[mt * 64 + lane];
            #pragma unroll
            for (int r2 = 0; r2 < 4; ++r2) {
                const int m = m0 + (int)kg * 4 + r2;
                float pc = pacc[r2] + other[r2] + bc;
                if constexpr (PRE) pc += pxc[r2];
                const float c = tanhf(pc);
                const float ho = h_fl[m * 16 + rc];
                const float hn = (1.f - zreg[r2]) * ho + zreg[r2] * c;
                h_fl[m * 16 + rc] = hn;
                const size_t idx = (size_t)m * HH + n;
                st2_cc(h_b + idx, hn);
                out[(size_t)t * BHH + idx] = hn;
                if (t == TT - 1) out[(size_t)TT * BHH + idx] = hn;
            }
        }
        const unsigned tg2 = 2u * (unsigned)t + 2u;
        gbar_arrive(bar, tg2);
        if (t + 1 < TT) {
            if constexpr (PRE) px = load_xp4(xp1, t + 1, m0, (int)kg, n);
            else px = mm_gx<HH>(x + (size_t)(t + 1) * BHH + arow, Wxi + browg, vzero);
        }
        gbar_wait(bar, tg2);
    }
}

// ---------------------------------------------------------------------------
extern "C" void kernel_launch(void* const* d_in, const int* in_sizes, int n_in,
                              void* d_out, int out_size, void* d_ws, size_t ws_size,
                              hipStream_t stream) {
    const float* x   = (const float*)d_in[0];
    const float* hid = (const float*)d_in[1];
    const float* Wzi = (const float*)d_in[2];
    const float* bzi = (const float*)d_in[3];
    const float* Wzh = (const float*)d_in[4];
    const float* bzh = (const float*)d_in[5];
    const float* Wri = (const float*)d_in[6];
    const float* bri = (const float*)d_in[7];
    const float* Wrh = (const float*)d_in[8];
    const float* brh = (const float*)d_in[9];
    const float* Wci = (const float*)d_in[10];
    const float* bci = (const float*)d_in[11];
    const float* Wch = (const float*)d_in[12];
    const float* bch = (const float*)d_in[13];
    float* out = (float*)d_out;

    char* ws = (char*)d_ws;
    const size_t WSZ = (size_t)HH * HH * sizeof(__bf16);   // 2 MB per matrix
    __bf16* Wzh_b = (__bf16*)(ws + 0 * WSZ);
    __bf16* Wzi_b = (__bf16*)(ws + 1 * WSZ);
    __bf16* Wrh_b = (__bf16*)(ws + 2 * WSZ);
    __bf16* Wri_b = (__bf16*)(ws + 3 * WSZ);
    __bf16* Wch_b = (__bf16*)(ws + 4 * WSZ);
    __bf16* Wci_b = (__bf16*)(ws + 5 * WSZ);
    char* p = ws + 6 * WSZ;
    __bf16*   h_b = (__bf16*)p;   p += (size_t)BHH * 2;    // 128 KB
    __bf16*   rh  = (__bf16*)p;   p += (size_t)BHH * 2;    // 128 KB
    unsigned* bar = (unsigned*)p; p += 256;                // count + gen
    const size_t XPSZ = (size_t)TT * BHH * sizeof(float);  // 128 MB each
    float* xpz = (float*)p;
    float* xpr = (float*)(p + XPSZ);
    float* xpc = (float*)(p + 2 * XPSZ);
    const size_t need_pre = (size_t)(p - ws) + 3 * XPSZ;
    const bool pre = ws_size >= need_pre;

    const int cvt_blocks = (HH * HH) / (256 * 4);   // 1024
    cvt_w<<<cvt_blocks, 256, 0, stream>>>(Wzh, Wzh_b);
    cvt_w<<<cvt_blocks, 256, 0, stream>>>(Wzi, Wzi_b);
    cvt_w<<<cvt_blocks, 256, 0, stream>>>(Wrh, Wrh_b);
    cvt_w<<<cvt_blocks, 256, 0, stream>>>(Wri, Wri_b);
    cvt_w<<<cvt_blocks, 256, 0, stream>>>(Wch, Wch_b);
    cvt_w<<<cvt_blocks, 256, 0, stream>>>(Wci, Wci_b);
    gru_init<<<BHH / 256, 256, 0, stream>>>(hid, h_b, bar);

    if (pre) {
        x_pre<<<512 * 16, 256, 0, stream>>>(x, Wzi_b, Wri_b, Wci_b,
                                            xpz, xpr, xpc);
        gru_fused<true><<<NWG, NT, 0, stream>>>(
            x, hid, Wzh_b, Wrh_b, Wch_b, Wzi_b, Wri_b, Wci_b,
            bzh, bzi, brh, bri, bch, bci,
            h_b, rh, bar, out, xpz, xpr, xpc);
    } else {
        gru_fused<false><<<NWG, NT, 0, stream>>>(
            x, hid, Wzh_b, Wrh_b, Wch_b, Wzi_b, Wri_b, Wci_b,
            bzh, bzi, brh, bri, bch, bci,
            h_b, rh, bar, out, xpz, xpr, xpc);
    }
}